// Round 7
// baseline (1754.631 us; speedup 1.0000x reference)
//
#include <hip/hip_runtime.h>
#include <cstdint>
#include <cstddef>

// ---------------------------------------------------------------------------
// QLoRABigNet: 6 blocks x (linear, relu, linear, relu, linear) + LayerNorm.
// D=1024, BATCH=16384. 18 bf16 MFMA GEMMs, LoRA merged into dequantized W.
//
// R11: A/B — LDS-FREE register-streaming GEMM vs proven LDS GEMM.
// Roofline insight: 128^2 LDS tile = 64 FLOP per staged byte; at ~56 B/cyc/CU
// L2 feed the MfmaUtil ceiling is 27% == measured 25-28%. The kernel is at
// its intensity roofline; schedules can't help (R5-R7 nulls explained).
// But THIS problem's W is 2 MB/layer = L2-resident, and a fragment row's
// kt-window is one 128B line (quad*8 + kk*32 elems) -> L1 dedups quad/kk
// reuse; waves/blocks share rows via per-CU L1. So arm X reads both MFMA
// operands DIRECTLY global->reg: no LDS, no barriers, compiler-scheduled,
// 16 waves/CU latency hiding. Same L2 bytes as staging, none of the stalls.
//   Blocks 0,2,4: gemm_reg_kernel (arm X).  Blocks 1,3,5: gemm_kernel LDS
//   SWAP=1 (arm Y; block 5 fp32 final path untouched).
// R10: lora precompute (B@A) + dequant float4-add; dequant <44.5us now.
// R8: bf16 pre-LN path. R9/R10: packed SWAP=1 epilogue (locked in).
// ---------------------------------------------------------------------------

typedef short  bf16x8 __attribute__((ext_vector_type(8)));   // 8 bf16 (4 VGPRs)
typedef float  f32x4  __attribute__((ext_vector_type(4)));

__device__ __forceinline__ unsigned short f2bf(float f) {
  unsigned int u = __builtin_bit_cast(unsigned int, f);
  u += 0x7FFFu + ((u >> 16) & 1u);
  return (unsigned short)(u >> 16);
}

__device__ __forceinline__ void async_copy16(void* lds, const void* g) {
  __builtin_amdgcn_global_load_lds(
      (const __attribute__((address_space(1))) void*)(uintptr_t)(g),
      (__attribute__((address_space(3))) void*)(unsigned int)(uintptr_t)(lds),
      16, 0, 0);
}

// ---------------------------------------------------------------------------
// LoRA precompute: LA[slot][o][i] = sum_r lora_b[slot][o][r]*lora_a[slot][r][i]
// grid (256, 3), block 256.
// ---------------------------------------------------------------------------
__global__ __launch_bounds__(256) void lora_kernel(
    const float* __restrict__ lora_a,    // [3][32][1024]
    const float* __restrict__ lora_b,    // [3][1024][32]
    float* __restrict__ LA) {            // [3][1024][1024]
  const int slot = blockIdx.y;
  const int o0   = blockIdx.x * 4;
  const int t    = threadIdx.x;
  const float* A = lora_a + slot * 32768 + t * 4;
  const float* B = lora_b + slot * 32768 + o0 * 32;

  float acc[4][4];
#pragma unroll
  for (int k = 0; k < 4; ++k)
#pragma unroll
    for (int j = 0; j < 4; ++j) acc[k][j] = 0.f;

#pragma unroll 8
  for (int r = 0; r < 32; ++r) {
    const float4 a4 = *(const float4*)(A + r * 1024);
#pragma unroll
    for (int k = 0; k < 4; ++k) {
      const float br = B[k * 32 + r];
      acc[k][0] = fmaf(br, a4.x, acc[k][0]);
      acc[k][1] = fmaf(br, a4.y, acc[k][1]);
      acc[k][2] = fmaf(br, a4.z, acc[k][2]);
      acc[k][3] = fmaf(br, a4.w, acc[k][3]);
    }
  }
#pragma unroll
  for (int k = 0; k < 4; ++k) {
    float4 o = make_float4(acc[k][0], acc[k][1], acc[k][2], acc[k][3]);
    *(float4*)(LA + (size_t)slot * 1048576 + (size_t)(o0 + k) * 1024 + t * 4) = o;
  }
}

// ---------------------------------------------------------------------------
// Dequant (+ precomputed-LoRA add). grid (256, 18), block 256.
// ---------------------------------------------------------------------------
__global__ __launch_bounds__(256) void dequant_kernel(
    const int* __restrict__ wq, const float* __restrict__ wn,
    const float* __restrict__ LA,        // [3][1024][1024] fp32 (B@A)
    unsigned short* __restrict__ Wbf) {
  const int l   = blockIdx.y;
  const int t   = threadIdx.x;
  const int blk = blockIdx.x;
  const long base = (long)l * 1048576;
  const float s = 2.0f / 15.0f;

  const int slot = (l == 0) ? 0 : (l == 6) ? 1 : (l == 12) ? 2 : -1;

  int4  q[4];
  float nrm[4];
  float4 c4[4];
#pragma unroll
  for (int k = 0; k < 4; ++k) {
    const int i4 = blk * 1024 + k * 256 + t;
    q[k]   = *(const int4*)(wq + base + (long)i4 * 4);
    nrm[k] = wn[l * 65536 + (i4 >> 2)];
  }
  if (slot >= 0) {
    const float* LAp = LA + (size_t)slot * 1048576;
#pragma unroll
    for (int k = 0; k < 4; ++k) {
      const int i4 = blk * 1024 + k * 256 + t;
      c4[k] = *(const float4*)(LAp + (size_t)i4 * 4);
    }
  }

  float v[4][4];
#pragma unroll
  for (int k = 0; k < 4; ++k) {
    v[k][0] = ((float)q[k].x * s - 1.0f) * nrm[k];
    v[k][1] = ((float)q[k].y * s - 1.0f) * nrm[k];
    v[k][2] = ((float)q[k].z * s - 1.0f) * nrm[k];
    v[k][3] = ((float)q[k].w * s - 1.0f) * nrm[k];
  }
  if (slot >= 0) {
#pragma unroll
    for (int k = 0; k < 4; ++k) {
      v[k][0] += c4[k].x; v[k][1] += c4[k].y;
      v[k][2] += c4[k].z; v[k][3] += c4[k].w;
    }
  }

#pragma unroll
  for (int k = 0; k < 4; ++k) {
    unsigned short u[4] = {f2bf(v[k][0]), f2bf(v[k][1]),
                           f2bf(v[k][2]), f2bf(v[k][3])};
    const long e0 = base + ((long)blk * 1024 + k * 256 + t) * 4;
    *(uint2*)(Wbf + e0) = *(uint2*)u;
  }
}

// ---------------------------------------------------------------------------
// fp32 -> bf16 for the initial x. grid 4096, block 256.
// ---------------------------------------------------------------------------
__global__ __launch_bounds__(256) void cvt_bf16_kernel(
    const float* __restrict__ in, unsigned short* __restrict__ out) {
  const long b0 = (long)blockIdx.x * 4096 + threadIdx.x * 4;
  float4 v[4];
#pragma unroll
  for (int k = 0; k < 4; ++k) v[k] = *(const float4*)(in + b0 + k * 1024);
#pragma unroll
  for (int k = 0; k < 4; ++k) {
    unsigned short u[4] = {f2bf(v[k].x), f2bf(v[k].y), f2bf(v[k].z), f2bf(v[k].w)};
    *(ushort4*)(out + b0 + k * 1024) = *(ushort4*)u;
  }
}

// ---------------------------------------------------------------------------
// ARM X: LDS-free register-streaming GEMM. out[m][n] = H[m][:]·W[n][:] + b.
// 128x128 tile, 4 waves (2x2, per-wave 64x64, acc[4][4]); both MFMA operands
// read global->reg (b128 per lane; one 128B line per row per kt serves all
// quad/kk fragments -> L1 dedup; W is L2-resident). No LDS, no barriers.
// MODE 0: relu + bf16. MODE 1: fp32. MODE 2: bf16 (no relu).
// ---------------------------------------------------------------------------
template <int MODE>
__global__ __launch_bounds__(256, 4) void gemm_reg_kernel(
    const unsigned short* __restrict__ H,
    const unsigned short* __restrict__ W,
    const float* __restrict__ bias,
    unsigned short* __restrict__ outb,
    float* __restrict__ outf) {
  constexpr int NN = 1024;
  const int tid = threadIdx.x;
  const int w   = tid >> 6;
  const int ln  = tid & 63;
  const int b   = blockIdx.x;
  const int m0  = ((b & 7) * 16 + (b >> 6)) * 128;
  const int n0  = ((b >> 3) & 7) * 128;

  const int quad = ln >> 4;
  const int lrow = ln & 15;
  const int wm   = (w >> 1) * 64;
  const int wn   = (w & 1) * 64;

  // lane's fragment base: row (base + mt*16 + lrow), k-offset quad*8 (+kk*32)
  const unsigned short* pA = H + (size_t)(m0 + wm + lrow) * 1024 + quad * 8;
  const unsigned short* pB = W + (size_t)(n0 + wn + lrow) * 1024 + quad * 8;

  f32x4 acc[4][4];
#pragma unroll
  for (int i = 0; i < 4; ++i)
#pragma unroll
    for (int j = 0; j < 4; ++j) acc[i][j] = (f32x4){0.f, 0.f, 0.f, 0.f};

  for (int kt = 0; kt < 16; ++kt) {
#pragma unroll
    for (int kk = 0; kk < 2; ++kk) {
      const int ko = kt * 64 + kk * 32;
      bf16x8 af[4], bg[4];
#pragma unroll
      for (int mt = 0; mt < 4; ++mt)
        af[mt] = *(const bf16x8*)(pA + (size_t)mt * 16384 + ko);
#pragma unroll
      for (int nt = 0; nt < 4; ++nt)
        bg[nt] = *(const bf16x8*)(pB + (size_t)nt * 16384 + ko);
#pragma unroll
      for (int mt = 0; mt < 4; ++mt)
#pragma unroll
        for (int nt = 0; nt < 4; ++nt)
          acc[mt][nt] = __builtin_amdgcn_mfma_f32_16x16x32_bf16(
              bg[nt], af[mt], acc[mt][nt], 0, 0, 0);   // SWAP operand order
    }
  }

  // packed epilogue: lane holds out[m=mt*16+lrow][n=nt*16+quad*4 + r]
#pragma unroll
  for (int mt = 0; mt < 4; ++mt) {
    const size_t row = (size_t)(m0 + wm + mt * 16 + lrow);
#pragma unroll
    for (int nt = 0; nt < 4; ++nt) {
      const int nb = n0 + wn + nt * 16 + quad * 4;
      const float4 bs = *(const float4*)(bias + nb);
      const f32x4 v = acc[mt][nt];
      float o0 = v[0] + bs.x, o1 = v[1] + bs.y;
      float o2 = v[2] + bs.z, o3 = v[3] + bs.w;
      if (MODE == 0) {
        o0 = fmaxf(o0, 0.0f); o1 = fmaxf(o1, 0.0f);
        o2 = fmaxf(o2, 0.0f); o3 = fmaxf(o3, 0.0f);
      }
      if (MODE == 1) {
        *(float4*)(outf + row * NN + nb) = make_float4(o0, o1, o2, o3);
      } else {
        unsigned short u[4] = {f2bf(o0), f2bf(o1), f2bf(o2), f2bf(o3)};
        *(uint2*)(outb + row * NN + nb) = *(uint2*)u;
      }
    }
  }
}

// ---------------------------------------------------------------------------
// ARM Y (proven): LDS-staged GEMM, 128x128, 4 waves, 4 blocks/CU, SWAP=1
// packed epilogue. grid 1024, block 256.
// ---------------------------------------------------------------------------
template <int MODE>
__global__ __launch_bounds__(256, 4) void gemm_kernel(
    const unsigned short* __restrict__ H,
    const unsigned short* __restrict__ W,
    const float* __restrict__ bias,
    unsigned short* __restrict__ outb,
    float* __restrict__ outf) {
  constexpr int K = 1024;
  constexpr int NN = 1024;

  __shared__ uint4 ldsq[2048];              // 32 KiB
  char* base = (char*)ldsq;

  const int tid = threadIdx.x;
  const int w   = tid >> 6;
  const int ln  = tid & 63;
  const int b   = blockIdx.x;
  const int m0  = ((b & 7) * 16 + (b >> 6)) * 128;
  const int n0  = ((b >> 3) & 7) * 128;

  const int gc = (ln & 7) ^ (ln >> 3);
  const unsigned short* gA = H + (size_t)(m0 + w * 32 + (ln >> 3)) * K + gc * 8;
  const unsigned short* gB = W + (size_t)(n0 + w * 32 + (ln >> 3)) * K + gc * 8;
  char* ldsA = base + w * 4096;
  char* ldsB = base + 16384 + w * 4096;

  const int quad = ln >> 4;
  const int lrow = ln & 15;
  const int sw   = lrow & 7;
  const int c0   = ((quad)     ^ sw) * 16;
  const int c1   = ((quad + 4) ^ sw) * 16;
  const int wm   = (w >> 1) * 64;
  const int wn   = (w & 1) * 64;
  const char* fragA = base + (wm + lrow) * 128;
  const char* fragB = base + 16384 + (wn + lrow) * 128;

  f32x4 acc[4][4];
#pragma unroll
  for (int i = 0; i < 4; ++i)
#pragma unroll
    for (int j = 0; j < 4; ++j) acc[i][j] = (f32x4){0.f, 0.f, 0.f, 0.f};

  for (int kt = 0; kt < 16; ++kt) {
    const unsigned short* pA = gA + kt * 64;
    const unsigned short* pB = gB + kt * 64;
#pragma unroll
    for (int i = 0; i < 4; ++i) {
      async_copy16(ldsA + i * 1024, pA + (size_t)i * 8 * K);
      async_copy16(ldsB + i * 1024, pB + (size_t)i * 8 * K);
    }
    __syncthreads();
#pragma unroll
    for (int kk = 0; kk < 2; ++kk) {
      const int co = kk ? c1 : c0;
      bf16x8 af[4], bg[4];
#pragma unroll
      for (int mt = 0; mt < 4; ++mt)
        af[mt] = *(const bf16x8*)(fragA + mt * 2048 + co);
#pragma unroll
      for (int nt = 0; nt < 4; ++nt)
        bg[nt] = *(const bf16x8*)(fragB + nt * 2048 + co);
#pragma unroll
      for (int mt = 0; mt < 4; ++mt)
#pragma unroll
        for (int nt = 0; nt < 4; ++nt)
          acc[mt][nt] = __builtin_amdgcn_mfma_f32_16x16x32_bf16(
              bg[nt], af[mt], acc[mt][nt], 0, 0, 0);
    }
    __syncthreads();
  }

#pragma unroll
  for (int mt = 0; mt < 4; ++mt) {
    const size_t row = (size_t)(m0 + wm + mt * 16 + lrow);
#pragma unroll
    for (int nt = 0; nt < 4; ++nt) {
      const int nb = n0 + wn + nt * 16 + quad * 4;
      const float4 bs = *(const float4*)(bias + nb);
      const f32x4 v = acc[mt][nt];
      float o0 = v[0] + bs.x, o1 = v[1] + bs.y;
      float o2 = v[2] + bs.z, o3 = v[3] + bs.w;
      if (MODE == 0) {
        o0 = fmaxf(o0, 0.0f); o1 = fmaxf(o1, 0.0f);
        o2 = fmaxf(o2, 0.0f); o3 = fmaxf(o3, 0.0f);
      }
      if (MODE == 1) {
        *(float4*)(outf + row * NN + nb) = make_float4(o0, o1, o2, o3);
      } else {
        unsigned short u[4] = {f2bf(o0), f2bf(o1), f2bf(o2), f2bf(o3)};
        *(uint2*)(outb + row * NN + nb) = *(uint2*)u;
      }
    }
  }
}

// ---------------------------------------------------------------------------
// LayerNorm (fp32 input; block 5 only). One WAVE per row. grid 4096, blk 256.
// ---------------------------------------------------------------------------
__global__ __launch_bounds__(256) void ln_kernel(
    const float* __restrict__ in, const float* __restrict__ lnw,
    const float* __restrict__ lnb, unsigned short* __restrict__ outb,
    float* __restrict__ outf, int wbf, int wf32) {
  const int wv = threadIdx.x >> 6;
  const int ln = threadIdx.x & 63;
  const int row = blockIdx.x * 4 + wv;
  const float* p = in + (size_t)row * 1024;

  float4 v[4];
  float s = 0.f, q = 0.f;
#pragma unroll
  for (int c = 0; c < 4; ++c) {
    v[c] = *(const float4*)(p + c * 256 + ln * 4);
    s += v[c].x + v[c].y + v[c].z + v[c].w;
    q += v[c].x * v[c].x + v[c].y * v[c].y + v[c].z * v[c].z + v[c].w * v[c].w;
  }
#pragma unroll
  for (int off = 32; off; off >>= 1) {
    s += __shfl_xor(s, off);
    q += __shfl_xor(q, off);
  }
  const float mu  = s * (1.0f / 1024.0f);
  const float var = q * (1.0f / 1024.0f) - mu * mu;
  const float rs  = rsqrtf(var + 1e-5f);

#pragma unroll
  for (int c = 0; c < 4; ++c) {
    const int col = c * 256 + ln * 4;
    const float4 w4 = *(const float4*)(lnw + col);
    const float4 b4 = *(const float4*)(lnb + col);
    const float y0 = (v[c].x - mu) * rs * w4.x + b4.x;
    const float y1 = (v[c].y - mu) * rs * w4.y + b4.y;
    const float y2 = (v[c].z - mu) * rs * w4.z + b4.z;
    const float y3 = (v[c].w - mu) * rs * w4.w + b4.w;
    if (wbf) {
      unsigned short u[4] = {f2bf(y0), f2bf(y1), f2bf(y2), f2bf(y3)};
      *(ushort4*)(outb + (size_t)row * 1024 + col) = *(ushort4*)u;
    }
    if (wf32) {
      float4 y = make_float4(y0, y1, y2, y3);
      *(float4*)(outf + (size_t)row * 1024 + col) = y;
    }
  }
}

// ---------------------------------------------------------------------------
// LayerNorm, bf16 in -> bf16 out (blocks 0-4). One WAVE per row.
// grid 4096, block 256.
// ---------------------------------------------------------------------------
__global__ __launch_bounds__(256) void ln_bf16_kernel(
    const unsigned short* __restrict__ in, const float* __restrict__ lnw,
    const float* __restrict__ lnb, unsigned short* __restrict__ outb) {
  const int wv = threadIdx.x >> 6;
  const int ln = threadIdx.x & 63;
  const int row = blockIdx.x * 4 + wv;
  const unsigned short* p = in + (size_t)row * 1024 + ln * 16;

  const uint4 r0 = *(const uint4*)(p);
  const uint4 r1 = *(const uint4*)(p + 8);
  const unsigned ru[8] = {r0.x, r0.y, r0.z, r0.w, r1.x, r1.y, r1.z, r1.w};

  float f[16];
#pragma unroll
  for (int i = 0; i < 8; ++i) {
    f[2 * i]     = __builtin_bit_cast(float, ru[i] << 16);
    f[2 * i + 1] = __builtin_bit_cast(float, ru[i] & 0xffff0000u);
  }

  float s = 0.f, q = 0.f;
#pragma unroll
  for (int i = 0; i < 16; ++i) { s += f[i]; q += f[i] * f[i]; }
#pragma unroll
  for (int off = 32; off; off >>= 1) {
    s += __shfl_xor(s, off);
    q += __shfl_xor(q, off);
  }
  const float mu  = s * (1.0f / 1024.0f);
  const float var = q * (1.0f / 1024.0f) - mu * mu;
  const float rs  = rsqrtf(var + 1e-5f);

  const float* wp = lnw + ln * 16;
  const float* bp = lnb + ln * 16;
  unsigned o[8];
#pragma unroll
  for (int i = 0; i < 8; ++i) {
    const float y0 = (f[2 * i]     - mu) * rs * wp[2 * i]     + bp[2 * i];
    const float y1 = (f[2 * i + 1] - mu) * rs * wp[2 * i + 1] + bp[2 * i + 1];
    o[i] = (unsigned)f2bf(y0) | ((unsigned)f2bf(y1) << 16);
  }
  unsigned short* dst = outb + (size_t)row * 1024 + ln * 16;
  *(uint4*)(dst)     = make_uint4(o[0], o[1], o[2], o[3]);
  *(uint4*)(dst + 8) = make_uint4(o[4], o[5], o[6], o[7]);
}

// ---------------------------------------------------------------------------
extern "C" void kernel_launch(void* const* d_in, const int* in_sizes, int n_in,
                              void* d_out, int out_size, void* d_ws, size_t ws_size,
                              hipStream_t stream) {
  const float* x    = (const float*)d_in[0];
  const int*   wq   = (const int*)d_in[1];
  const float* wn   = (const float*)d_in[2];
  const float* bias = (const float*)d_in[3];
  const float* la   = (const float*)d_in[4];
  const float* lb   = (const float*)d_in[5];
  const float* lnw  = (const float*)d_in[6];
  const float* lnb  = (const float*)d_in[7];
  float* out = (float*)d_out;

  char* ws = (char*)d_ws;
  unsigned short* Wbf = (unsigned short*)ws;                         // 37.75 MB
  unsigned short* hA  = (unsigned short*)(ws + 37748736);            // 32 MB
  unsigned short* hB  = (unsigned short*)(ws + 37748736 + 33554432); // 32 MB
  float* LA = (float*)hB;   // 12 MB, consumed by dequant before hB is written

  lora_kernel<<<dim3(256, 3), 256, 0, stream>>>(la, lb, LA);
  dequant_kernel<<<dim3(256, 18), 256, 0, stream>>>(wq, wn, LA, Wbf);
  cvt_bf16_kernel<<<4096, 256, 0, stream>>>(x, hA);

  for (int blk = 0; blk < 6; ++blk) {
    const int l = blk * 3;
    if ((blk & 1) == 0) {
      // ARM X: LDS-free register-streaming GEMM
      gemm_reg_kernel<0><<<1024, 256, 0, stream>>>(
          hA, Wbf + (size_t)l * 1048576, bias + l * 1024, hB, nullptr);
      gemm_reg_kernel<0><<<1024, 256, 0, stream>>>(
          hB, Wbf + (size_t)(l + 1) * 1048576, bias + (l + 1) * 1024, hA, nullptr);
      gemm_reg_kernel<2><<<1024, 256, 0, stream>>>(
          hA, Wbf + (size_t)(l + 2) * 1048576, bias + (l + 2) * 1024, hB, nullptr);
      ln_bf16_kernel<<<4096, 256, 0, stream>>>(
          hB, lnw + blk * 1024, lnb + blk * 1024, hA);
    } else if (blk < 5) {
      // ARM Y: proven LDS GEMM
      gemm_kernel<0><<<1024, 256, 0, stream>>>(
          hA, Wbf + (size_t)l * 1048576, bias + l * 1024, hB, nullptr);
      gemm_kernel<0><<<1024, 256, 0, stream>>>(
          hB, Wbf + (size_t)(l + 1) * 1048576, bias + (l + 1) * 1024, hA, nullptr);
      gemm_kernel<2><<<1024, 256, 0, stream>>>(
          hA, Wbf + (size_t)(l + 2) * 1048576, bias + (l + 2) * 1024, hB, nullptr);
      ln_bf16_kernel<<<4096, 256, 0, stream>>>(
          hB, lnw + blk * 1024, lnb + blk * 1024, hA);
    } else {
      // block 5: ARM Y + exact fp32 final path
      gemm_kernel<0><<<1024, 256, 0, stream>>>(
          hA, Wbf + (size_t)l * 1048576, bias + l * 1024, hB, nullptr);
      gemm_kernel<0><<<1024, 256, 0, stream>>>(
          hB, Wbf + (size_t)(l + 1) * 1048576, bias + (l + 1) * 1024, hA, nullptr);
      gemm_kernel<1><<<1024, 256, 0, stream>>>(
          hA, Wbf + (size_t)(l + 2) * 1048576, bias + (l + 2) * 1024, nullptr, out);
      ln_kernel<<<4096, 256, 0, stream>>>(
          out, lnw + blk * 1024, lnb + blk * 1024, nullptr, out, 0, 1);
    }
  }
}

// Round 8
// 971.470 us; speedup vs baseline: 1.8062x; 1.8062x over previous
//
#include <hip/hip_runtime.h>
#include <cstdint>
#include <cstddef>

// ---------------------------------------------------------------------------
// QLoRABigNet: 6 blocks x (linear, relu, linear, relu, linear) + LayerNorm.
// D=1024, BATCH=16384. 18 bf16 MFMA GEMMs, LoRA merged into dequantized W.
//
// R12: A/B — 256x128 tile (gemm_wide, blocks 0/2/4) vs proven 128x128
// (blocks 1/3/5). Corrected roofline: staged-feed floor ~15us vs measured
// 44us -> NOT BW-bound; it's the m97-structure barrier stall. gemm_wide
// keeps the exact proven skeleton (2 barriers/kt, async_copy16, XOR chunk
// swizzle, 64x64/wave acc[4][4]) but: staged bytes -25%, barrier episodes
// per CU -50% (2 blocks/CU x 32 vs 4 x 16). 8 waves (4m x 2n), 48KB LDS.
// CLOSED paths: reg-streaming (R11: 130us, L1 request-rate bound);
// 256^2 hand-pipelines (R5-R7: >= 49us); LDS-free and frag-lead schedules.
// R10: lora precompute + dequant float4-add. R8: bf16 pre-LN path.
// R9/R10: SWAP=1 packed epilogue (uint2/float4 stores).
// ---------------------------------------------------------------------------

typedef short  bf16x8 __attribute__((ext_vector_type(8)));   // 8 bf16 (4 VGPRs)
typedef float  f32x4  __attribute__((ext_vector_type(4)));

__device__ __forceinline__ unsigned short f2bf(float f) {
  unsigned int u = __builtin_bit_cast(unsigned int, f);
  u += 0x7FFFu + ((u >> 16) & 1u);
  return (unsigned short)(u >> 16);
}

__device__ __forceinline__ void async_copy16(void* lds, const void* g) {
  __builtin_amdgcn_global_load_lds(
      (const __attribute__((address_space(1))) void*)(uintptr_t)(g),
      (__attribute__((address_space(3))) void*)(unsigned int)(uintptr_t)(lds),
      16, 0, 0);
}

// ---------------------------------------------------------------------------
// LoRA precompute: LA[slot][o][i] = sum_r lora_b[slot][o][r]*lora_a[slot][r][i]
// grid (256, 3), block 256.
// ---------------------------------------------------------------------------
__global__ __launch_bounds__(256) void lora_kernel(
    const float* __restrict__ lora_a,    // [3][32][1024]
    const float* __restrict__ lora_b,    // [3][1024][32]
    float* __restrict__ LA) {            // [3][1024][1024]
  const int slot = blockIdx.y;
  const int o0   = blockIdx.x * 4;
  const int t    = threadIdx.x;
  const float* A = lora_a + slot * 32768 + t * 4;
  const float* B = lora_b + slot * 32768 + o0 * 32;

  float acc[4][4];
#pragma unroll
  for (int k = 0; k < 4; ++k)
#pragma unroll
    for (int j = 0; j < 4; ++j) acc[k][j] = 0.f;

#pragma unroll 8
  for (int r = 0; r < 32; ++r) {
    const float4 a4 = *(const float4*)(A + r * 1024);
#pragma unroll
    for (int k = 0; k < 4; ++k) {
      const float br = B[k * 32 + r];
      acc[k][0] = fmaf(br, a4.x, acc[k][0]);
      acc[k][1] = fmaf(br, a4.y, acc[k][1]);
      acc[k][2] = fmaf(br, a4.z, acc[k][2]);
      acc[k][3] = fmaf(br, a4.w, acc[k][3]);
    }
  }
#pragma unroll
  for (int k = 0; k < 4; ++k) {
    float4 o = make_float4(acc[k][0], acc[k][1], acc[k][2], acc[k][3]);
    *(float4*)(LA + (size_t)slot * 1048576 + (size_t)(o0 + k) * 1024 + t * 4) = o;
  }
}

// ---------------------------------------------------------------------------
// Dequant (+ precomputed-LoRA add). grid (256, 18), block 256.
// ---------------------------------------------------------------------------
__global__ __launch_bounds__(256) void dequant_kernel(
    const int* __restrict__ wq, const float* __restrict__ wn,
    const float* __restrict__ LA,        // [3][1024][1024] fp32 (B@A)
    unsigned short* __restrict__ Wbf) {
  const int l   = blockIdx.y;
  const int t   = threadIdx.x;
  const int blk = blockIdx.x;
  const long base = (long)l * 1048576;
  const float s = 2.0f / 15.0f;

  const int slot = (l == 0) ? 0 : (l == 6) ? 1 : (l == 12) ? 2 : -1;

  int4  q[4];
  float nrm[4];
  float4 c4[4];
#pragma unroll
  for (int k = 0; k < 4; ++k) {
    const int i4 = blk * 1024 + k * 256 + t;
    q[k]   = *(const int4*)(wq + base + (long)i4 * 4);
    nrm[k] = wn[l * 65536 + (i4 >> 2)];
  }
  if (slot >= 0) {
    const float* LAp = LA + (size_t)slot * 1048576;
#pragma unroll
    for (int k = 0; k < 4; ++k) {
      const int i4 = blk * 1024 + k * 256 + t;
      c4[k] = *(const float4*)(LAp + (size_t)i4 * 4);
    }
  }

  float v[4][4];
#pragma unroll
  for (int k = 0; k < 4; ++k) {
    v[k][0] = ((float)q[k].x * s - 1.0f) * nrm[k];
    v[k][1] = ((float)q[k].y * s - 1.0f) * nrm[k];
    v[k][2] = ((float)q[k].z * s - 1.0f) * nrm[k];
    v[k][3] = ((float)q[k].w * s - 1.0f) * nrm[k];
  }
  if (slot >= 0) {
#pragma unroll
    for (int k = 0; k < 4; ++k) {
      v[k][0] += c4[k].x; v[k][1] += c4[k].y;
      v[k][2] += c4[k].z; v[k][3] += c4[k].w;
    }
  }

#pragma unroll
  for (int k = 0; k < 4; ++k) {
    unsigned short u[4] = {f2bf(v[k][0]), f2bf(v[k][1]),
                           f2bf(v[k][2]), f2bf(v[k][3])};
    const long e0 = base + ((long)blk * 1024 + k * 256 + t) * 4;
    *(uint2*)(Wbf + e0) = *(uint2*)u;
  }
}

// ---------------------------------------------------------------------------
// fp32 -> bf16 for the initial x. grid 4096, block 256.
// ---------------------------------------------------------------------------
__global__ __launch_bounds__(256) void cvt_bf16_kernel(
    const float* __restrict__ in, unsigned short* __restrict__ out) {
  const long b0 = (long)blockIdx.x * 4096 + threadIdx.x * 4;
  float4 v[4];
#pragma unroll
  for (int k = 0; k < 4; ++k) v[k] = *(const float4*)(in + b0 + k * 1024);
#pragma unroll
  for (int k = 0; k < 4; ++k) {
    unsigned short u[4] = {f2bf(v[k].x), f2bf(v[k].y), f2bf(v[k].z), f2bf(v[k].w)};
    *(ushort4*)(out + b0 + k * 1024) = *(ushort4*)u;
  }
}

// ---------------------------------------------------------------------------
// ARM X: 256x128 tile, BK=64, 8 waves (4m x 2n, 64x64 each), 48 KB LDS,
// grid 512 (2 blocks/CU). Same 2-barrier skeleton + XOR chunk swizzle +
// SWAP packed epilogue as the proven kernel. MODE 0 relu bf16 / 2 bf16.
// ---------------------------------------------------------------------------
template <int MODE>
__global__ __launch_bounds__(512, 4) void gemm_wide_kernel(
    const unsigned short* __restrict__ H,
    const unsigned short* __restrict__ W,
    const float* __restrict__ bias,
    unsigned short* __restrict__ outb,
    float* __restrict__ outf) {
  constexpr int K = 1024;
  constexpr int NN = 1024;

  __shared__ uint4 ldsq[3072];              // 48 KiB: A[0,32K) B[32K,48K)
  char* base = (char*)ldsq;

  const int tid = threadIdx.x;
  const int w   = tid >> 6;                 // 0..7
  const int ln  = tid & 63;
  const int b   = blockIdx.x;
  const int s   = (b & 7) * 64 + (b >> 3);  // XCD swizzle (512 % 8 == 0)
  const int m0  = (s >> 3) * 256;
  const int n0  = (s & 7) * 128;

  // staging: thread covers row base + w*8 + (ln>>3), phys chunk ln&7,
  // global chunk gc = (ln&7) ^ (row&7); row bases are multiples of 64.
  const int gc = (ln & 7) ^ ((ln >> 3) & 7);
  const unsigned short* gA = H + (size_t)(m0 + w * 8 + (ln >> 3)) * K + gc * 8;
  const unsigned short* gB = W + (size_t)(n0 + w * 8 + (ln >> 3)) * K + gc * 8;
  char* ldsA = base + w * 1024;             // + i*8192 per 64-row round
  char* ldsB = base + 32768 + w * 1024;     // + j*8192

  const int quad = ln >> 4;
  const int lrow = ln & 15;
  const int sw   = lrow & 7;
  const int c0   = ((quad)     ^ sw) * 16;
  const int c1   = ((quad + 4) ^ sw) * 16;
  const int wm   = (w >> 1) * 64;           // 0,64,128,192
  const int wn   = (w & 1) * 64;            // 0,64
  const char* fragA = base + (wm + lrow) * 128;
  const char* fragB = base + 32768 + (wn + lrow) * 128;

  f32x4 acc[4][4];
#pragma unroll
  for (int i = 0; i < 4; ++i)
#pragma unroll
    for (int j = 0; j < 4; ++j) acc[i][j] = (f32x4){0.f, 0.f, 0.f, 0.f};

  for (int kt = 0; kt < 16; ++kt) {
    const unsigned short* pA = gA + kt * 64;
    const unsigned short* pB = gB + kt * 64;
#pragma unroll
    for (int i = 0; i < 4; ++i)
      async_copy16(ldsA + i * 8192, pA + (size_t)i * 64 * K);
#pragma unroll
    for (int j = 0; j < 2; ++j)
      async_copy16(ldsB + j * 8192, pB + (size_t)j * 64 * K);
    __syncthreads();
#pragma unroll
    for (int kk = 0; kk < 2; ++kk) {
      const int co = kk ? c1 : c0;
      bf16x8 af[4], bg[4];
#pragma unroll
      for (int mt = 0; mt < 4; ++mt)
        af[mt] = *(const bf16x8*)(fragA + mt * 2048 + co);
#pragma unroll
      for (int nt = 0; nt < 4; ++nt)
        bg[nt] = *(const bf16x8*)(fragB + nt * 2048 + co);
#pragma unroll
      for (int mt = 0; mt < 4; ++mt)
#pragma unroll
        for (int nt = 0; nt < 4; ++nt)
          acc[mt][nt] = __builtin_amdgcn_mfma_f32_16x16x32_bf16(
              bg[nt], af[mt], acc[mt][nt], 0, 0, 0);
    }
    __syncthreads();
  }

  // packed epilogue: lane holds out[m=mt*16+lrow][n=nt*16+quad*4+r]
#pragma unroll
  for (int mt = 0; mt < 4; ++mt) {
    const size_t row = (size_t)(m0 + wm + mt * 16 + lrow);
#pragma unroll
    for (int nt = 0; nt < 4; ++nt) {
      const int nb = n0 + wn + nt * 16 + quad * 4;
      const float4 bs = *(const float4*)(bias + nb);
      const f32x4 v = acc[mt][nt];
      float o0 = v[0] + bs.x, o1 = v[1] + bs.y;
      float o2 = v[2] + bs.z, o3 = v[3] + bs.w;
      if (MODE == 0) {
        o0 = fmaxf(o0, 0.0f); o1 = fmaxf(o1, 0.0f);
        o2 = fmaxf(o2, 0.0f); o3 = fmaxf(o3, 0.0f);
      }
      if (MODE == 1) {
        *(float4*)(outf + row * NN + nb) = make_float4(o0, o1, o2, o3);
      } else {
        unsigned short u[4] = {f2bf(o0), f2bf(o1), f2bf(o2), f2bf(o3)};
        *(uint2*)(outb + row * NN + nb) = *(uint2*)u;
      }
    }
  }
}

// ---------------------------------------------------------------------------
// ARM Y (proven): 128x128, 4 waves, 4 blocks/CU, SWAP packed epilogue.
// grid 1024, block 256.
// ---------------------------------------------------------------------------
template <int MODE>
__global__ __launch_bounds__(256, 4) void gemm_kernel(
    const unsigned short* __restrict__ H,
    const unsigned short* __restrict__ W,
    const float* __restrict__ bias,
    unsigned short* __restrict__ outb,
    float* __restrict__ outf) {
  constexpr int K = 1024;
  constexpr int NN = 1024;

  __shared__ uint4 ldsq[2048];              // 32 KiB
  char* base = (char*)ldsq;

  const int tid = threadIdx.x;
  const int w   = tid >> 6;
  const int ln  = tid & 63;
  const int b   = blockIdx.x;
  const int m0  = ((b & 7) * 16 + (b >> 6)) * 128;
  const int n0  = ((b >> 3) & 7) * 128;

  const int gc = (ln & 7) ^ (ln >> 3);
  const unsigned short* gA = H + (size_t)(m0 + w * 32 + (ln >> 3)) * K + gc * 8;
  const unsigned short* gB = W + (size_t)(n0 + w * 32 + (ln >> 3)) * K + gc * 8;
  char* ldsA = base + w * 4096;
  char* ldsB = base + 16384 + w * 4096;

  const int quad = ln >> 4;
  const int lrow = ln & 15;
  const int sw   = lrow & 7;
  const int c0   = ((quad)     ^ sw) * 16;
  const int c1   = ((quad + 4) ^ sw) * 16;
  const int wm   = (w >> 1) * 64;
  const int wn   = (w & 1) * 64;
  const char* fragA = base + (wm + lrow) * 128;
  const char* fragB = base + 16384 + (wn + lrow) * 128;

  f32x4 acc[4][4];
#pragma unroll
  for (int i = 0; i < 4; ++i)
#pragma unroll
    for (int j = 0; j < 4; ++j) acc[i][j] = (f32x4){0.f, 0.f, 0.f, 0.f};

  for (int kt = 0; kt < 16; ++kt) {
    const unsigned short* pA = gA + kt * 64;
    const unsigned short* pB = gB + kt * 64;
#pragma unroll
    for (int i = 0; i < 4; ++i) {
      async_copy16(ldsA + i * 1024, pA + (size_t)i * 8 * K);
      async_copy16(ldsB + i * 1024, pB + (size_t)i * 8 * K);
    }
    __syncthreads();
#pragma unroll
    for (int kk = 0; kk < 2; ++kk) {
      const int co = kk ? c1 : c0;
      bf16x8 af[4], bg[4];
#pragma unroll
      for (int mt = 0; mt < 4; ++mt)
        af[mt] = *(const bf16x8*)(fragA + mt * 2048 + co);
#pragma unroll
      for (int nt = 0; nt < 4; ++nt)
        bg[nt] = *(const bf16x8*)(fragB + nt * 2048 + co);
#pragma unroll
      for (int mt = 0; mt < 4; ++mt)
#pragma unroll
        for (int nt = 0; nt < 4; ++nt)
          acc[mt][nt] = __builtin_amdgcn_mfma_f32_16x16x32_bf16(
              bg[nt], af[mt], acc[mt][nt], 0, 0, 0);
    }
    __syncthreads();
  }

#pragma unroll
  for (int mt = 0; mt < 4; ++mt) {
    const size_t row = (size_t)(m0 + wm + mt * 16 + lrow);
#pragma unroll
    for (int nt = 0; nt < 4; ++nt) {
      const int nb = n0 + wn + nt * 16 + quad * 4;
      const float4 bs = *(const float4*)(bias + nb);
      const f32x4 v = acc[mt][nt];
      float o0 = v[0] + bs.x, o1 = v[1] + bs.y;
      float o2 = v[2] + bs.z, o3 = v[3] + bs.w;
      if (MODE == 0) {
        o0 = fmaxf(o0, 0.0f); o1 = fmaxf(o1, 0.0f);
        o2 = fmaxf(o2, 0.0f); o3 = fmaxf(o3, 0.0f);
      }
      if (MODE == 1) {
        *(float4*)(outf + row * NN + nb) = make_float4(o0, o1, o2, o3);
      } else {
        unsigned short u[4] = {f2bf(o0), f2bf(o1), f2bf(o2), f2bf(o3)};
        *(uint2*)(outb + row * NN + nb) = *(uint2*)u;
      }
    }
  }
}

// ---------------------------------------------------------------------------
// LayerNorm (fp32 input; block 5 only). One WAVE per row. grid 4096, blk 256.
// ---------------------------------------------------------------------------
__global__ __launch_bounds__(256) void ln_kernel(
    const float* __restrict__ in, const float* __restrict__ lnw,
    const float* __restrict__ lnb, unsigned short* __restrict__ outb,
    float* __restrict__ outf, int wbf, int wf32) {
  const int wv = threadIdx.x >> 6;
  const int ln = threadIdx.x & 63;
  const int row = blockIdx.x * 4 + wv;
  const float* p = in + (size_t)row * 1024;

  float4 v[4];
  float s = 0.f, q = 0.f;
#pragma unroll
  for (int c = 0; c < 4; ++c) {
    v[c] = *(const float4*)(p + c * 256 + ln * 4);
    s += v[c].x + v[c].y + v[c].z + v[c].w;
    q += v[c].x * v[c].x + v[c].y * v[c].y + v[c].z * v[c].z + v[c].w * v[c].w;
  }
#pragma unroll
  for (int off = 32; off; off >>= 1) {
    s += __shfl_xor(s, off);
    q += __shfl_xor(q, off);
  }
  const float mu  = s * (1.0f / 1024.0f);
  const float var = q * (1.0f / 1024.0f) - mu * mu;
  const float rs  = rsqrtf(var + 1e-5f);

#pragma unroll
  for (int c = 0; c < 4; ++c) {
    const int col = c * 256 + ln * 4;
    const float4 w4 = *(const float4*)(lnw + col);
    const float4 b4 = *(const float4*)(lnb + col);
    const float y0 = (v[c].x - mu) * rs * w4.x + b4.x;
    const float y1 = (v[c].y - mu) * rs * w4.y + b4.y;
    const float y2 = (v[c].z - mu) * rs * w4.z + b4.z;
    const float y3 = (v[c].w - mu) * rs * w4.w + b4.w;
    if (wbf) {
      unsigned short u[4] = {f2bf(y0), f2bf(y1), f2bf(y2), f2bf(y3)};
      *(ushort4*)(outb + (size_t)row * 1024 + col) = *(ushort4*)u;
    }
    if (wf32) {
      float4 y = make_float4(y0, y1, y2, y3);
      *(float4*)(outf + (size_t)row * 1024 + col) = y;
    }
  }
}

// ---------------------------------------------------------------------------
// LayerNorm, bf16 in -> bf16 out (blocks 0-4). One WAVE per row.
// grid 4096, block 256.
// ---------------------------------------------------------------------------
__global__ __launch_bounds__(256) void ln_bf16_kernel(
    const unsigned short* __restrict__ in, const float* __restrict__ lnw,
    const float* __restrict__ lnb, unsigned short* __restrict__ outb) {
  const int wv = threadIdx.x >> 6;
  const int ln = threadIdx.x & 63;
  const int row = blockIdx.x * 4 + wv;
  const unsigned short* p = in + (size_t)row * 1024 + ln * 16;

  const uint4 r0 = *(const uint4*)(p);
  const uint4 r1 = *(const uint4*)(p + 8);
  const unsigned ru[8] = {r0.x, r0.y, r0.z, r0.w, r1.x, r1.y, r1.z, r1.w};

  float f[16];
#pragma unroll
  for (int i = 0; i < 8; ++i) {
    f[2 * i]     = __builtin_bit_cast(float, ru[i] << 16);
    f[2 * i + 1] = __builtin_bit_cast(float, ru[i] & 0xffff0000u);
  }

  float s = 0.f, q = 0.f;
#pragma unroll
  for (int i = 0; i < 16; ++i) { s += f[i]; q += f[i] * f[i]; }
#pragma unroll
  for (int off = 32; off; off >>= 1) {
    s += __shfl_xor(s, off);
    q += __shfl_xor(q, off);
  }
  const float mu  = s * (1.0f / 1024.0f);
  const float var = q * (1.0f / 1024.0f) - mu * mu;
  const float rs  = rsqrtf(var + 1e-5f);

  const float* wp = lnw + ln * 16;
  const float* bp = lnb + ln * 16;
  unsigned o[8];
#pragma unroll
  for (int i = 0; i < 8; ++i) {
    const float y0 = (f[2 * i]     - mu) * rs * wp[2 * i]     + bp[2 * i];
    const float y1 = (f[2 * i + 1] - mu) * rs * wp[2 * i + 1] + bp[2 * i + 1];
    o[i] = (unsigned)f2bf(y0) | ((unsigned)f2bf(y1) << 16);
  }
  unsigned short* dst = outb + (size_t)row * 1024 + ln * 16;
  *(uint4*)(dst)     = make_uint4(o[0], o[1], o[2], o[3]);
  *(uint4*)(dst + 8) = make_uint4(o[4], o[5], o[6], o[7]);
}

// ---------------------------------------------------------------------------
extern "C" void kernel_launch(void* const* d_in, const int* in_sizes, int n_in,
                              void* d_out, int out_size, void* d_ws, size_t ws_size,
                              hipStream_t stream) {
  const float* x    = (const float*)d_in[0];
  const int*   wq   = (const int*)d_in[1];
  const float* wn   = (const float*)d_in[2];
  const float* bias = (const float*)d_in[3];
  const float* la   = (const float*)d_in[4];
  const float* lb   = (const float*)d_in[5];
  const float* lnw  = (const float*)d_in[6];
  const float* lnb  = (const float*)d_in[7];
  float* out = (float*)d_out;

  char* ws = (char*)d_ws;
  unsigned short* Wbf = (unsigned short*)ws;                         // 37.75 MB
  unsigned short* hA  = (unsigned short*)(ws + 37748736);            // 32 MB
  unsigned short* hB  = (unsigned short*)(ws + 37748736 + 33554432); // 32 MB
  float* LA = (float*)hB;   // 12 MB, consumed by dequant before hB is written

  lora_kernel<<<dim3(256, 3), 256, 0, stream>>>(la, lb, LA);
  dequant_kernel<<<dim3(256, 18), 256, 0, stream>>>(wq, wn, LA, Wbf);
  cvt_bf16_kernel<<<4096, 256, 0, stream>>>(x, hA);

  for (int blk = 0; blk < 6; ++blk) {
    const int l = blk * 3;
    if ((blk & 1) == 0) {
      // ARM X: 256x128 wide tile
      gemm_wide_kernel<0><<<512, 512, 0, stream>>>(
          hA, Wbf + (size_t)l * 1048576, bias + l * 1024, hB, nullptr);
      gemm_wide_kernel<0><<<512, 512, 0, stream>>>(
          hB, Wbf + (size_t)(l + 1) * 1048576, bias + (l + 1) * 1024, hA, nullptr);
      gemm_wide_kernel<2><<<512, 512, 0, stream>>>(
          hA, Wbf + (size_t)(l + 2) * 1048576, bias + (l + 2) * 1024, hB, nullptr);
      ln_bf16_kernel<<<4096, 256, 0, stream>>>(
          hB, lnw + blk * 1024, lnb + blk * 1024, hA);
    } else if (blk < 5) {
      // ARM Y: proven 128^2
      gemm_kernel<0><<<1024, 256, 0, stream>>>(
          hA, Wbf + (size_t)l * 1048576, bias + l * 1024, hB, nullptr);
      gemm_kernel<0><<<1024, 256, 0, stream>>>(
          hB, Wbf + (size_t)(l + 1) * 1048576, bias + (l + 1) * 1024, hA, nullptr);
      gemm_kernel<2><<<1024, 256, 0, stream>>>(
          hA, Wbf + (size_t)(l + 2) * 1048576, bias + (l + 2) * 1024, hB, nullptr);
      ln_bf16_kernel<<<4096, 256, 0, stream>>>(
          hB, lnw + blk * 1024, lnb + blk * 1024, hA);
    } else {
      // block 5: proven + exact fp32 final path
      gemm_kernel<0><<<1024, 256, 0, stream>>>(
          hA, Wbf + (size_t)l * 1048576, bias + l * 1024, hB, nullptr);
      gemm_kernel<0><<<1024, 256, 0, stream>>>(
          hB, Wbf + (size_t)(l + 1) * 1048576, bias + (l + 1) * 1024, hA, nullptr);
      gemm_kernel<1><<<1024, 256, 0, stream>>>(
          hA, Wbf + (size_t)(l + 2) * 1048576, bias + (l + 2) * 1024, nullptr, out);
      ln_kernel<<<4096, 256, 0, stream>>>(
          out, lnw + blk * 1024, lnb + blk * 1024, nullptr, out, 0, 1);
    }
  }
}

// Round 9
// 880.345 us; speedup vs baseline: 1.9931x; 1.1035x over previous
//
#include <hip/hip_runtime.h>
#include <cstdint>
#include <cstddef>

// ---------------------------------------------------------------------------
// QLoRABigNet: 6 blocks x (linear, relu, linear, relu, linear) + LayerNorm.
// D=1024, BATCH=16384. 18 bf16 MFMA GEMMs, LoRA merged into dequantized W.
//
// R13: CONSOLIDATION of all A/B-verified winners:
//  - GEMM: proven 128^2 tile, BK=64, 4 waves, 4 blocks/CU, SWAP=0 scalar
//    epilogue. Cross-round totals (R4=922.5 all-SWAP0 vs R5=985.9 all-SWAP1,
//    noise +-5us on config-identical repeats R0/R3) prove the packed SWAP=1
//    epilogue is a ~3.5us/GEMM regression despite halving WRITE_SIZE.
//  - lora_kernel precompute (B@A) + dequant float4-add (R10: dequant 46us ->
//    below 44.5 cutoff).
//  - bf16 pre-LN intermediate blocks 0-4 (R8: -46us); exact fp32 block 5.
// CLOSED: 256^2 hand-pipelines (R5-R7), frag-lead (R6), reg-streaming
// (R11: L1 request-rate bound, 130us), 256x128 wide tile (R12: neutral),
// SWAP=1 epilogue (R5/R9: regression).
// ---------------------------------------------------------------------------

typedef short  bf16x8 __attribute__((ext_vector_type(8)));   // 8 bf16 (4 VGPRs)
typedef float  f32x4  __attribute__((ext_vector_type(4)));

__device__ __forceinline__ unsigned short f2bf(float f) {
  unsigned int u = __builtin_bit_cast(unsigned int, f);
  u += 0x7FFFu + ((u >> 16) & 1u);
  return (unsigned short)(u >> 16);
}

__device__ __forceinline__ void async_copy16(void* lds, const void* g) {
  __builtin_amdgcn_global_load_lds(
      (const __attribute__((address_space(1))) void*)(uintptr_t)(g),
      (__attribute__((address_space(3))) void*)(unsigned int)(uintptr_t)(lds),
      16, 0, 0);
}

// ---------------------------------------------------------------------------
// LoRA precompute: LA[slot][o][i] = sum_r lora_b[slot][o][r]*lora_a[slot][r][i]
// grid (256, 3), block 256.
// ---------------------------------------------------------------------------
__global__ __launch_bounds__(256) void lora_kernel(
    const float* __restrict__ lora_a,    // [3][32][1024]
    const float* __restrict__ lora_b,    // [3][1024][32]
    float* __restrict__ LA) {            // [3][1024][1024]
  const int slot = blockIdx.y;
  const int o0   = blockIdx.x * 4;
  const int t    = threadIdx.x;
  const float* A = lora_a + slot * 32768 + t * 4;
  const float* B = lora_b + slot * 32768 + o0 * 32;

  float acc[4][4];
#pragma unroll
  for (int k = 0; k < 4; ++k)
#pragma unroll
    for (int j = 0; j < 4; ++j) acc[k][j] = 0.f;

#pragma unroll 8
  for (int r = 0; r < 32; ++r) {
    const float4 a4 = *(const float4*)(A + r * 1024);
#pragma unroll
    for (int k = 0; k < 4; ++k) {
      const float br = B[k * 32 + r];
      acc[k][0] = fmaf(br, a4.x, acc[k][0]);
      acc[k][1] = fmaf(br, a4.y, acc[k][1]);
      acc[k][2] = fmaf(br, a4.z, acc[k][2]);
      acc[k][3] = fmaf(br, a4.w, acc[k][3]);
    }
  }
#pragma unroll
  for (int k = 0; k < 4; ++k) {
    float4 o = make_float4(acc[k][0], acc[k][1], acc[k][2], acc[k][3]);
    *(float4*)(LA + (size_t)slot * 1048576 + (size_t)(o0 + k) * 1024 + t * 4) = o;
  }
}

// ---------------------------------------------------------------------------
// Dequant (+ precomputed-LoRA add). grid (256, 18), block 256.
// ---------------------------------------------------------------------------
__global__ __launch_bounds__(256) void dequant_kernel(
    const int* __restrict__ wq, const float* __restrict__ wn,
    const float* __restrict__ LA,        // [3][1024][1024] fp32 (B@A)
    unsigned short* __restrict__ Wbf) {
  const int l   = blockIdx.y;
  const int t   = threadIdx.x;
  const int blk = blockIdx.x;
  const long base = (long)l * 1048576;
  const float s = 2.0f / 15.0f;

  const int slot = (l == 0) ? 0 : (l == 6) ? 1 : (l == 12) ? 2 : -1;

  int4  q[4];
  float nrm[4];
  float4 c4[4];
#pragma unroll
  for (int k = 0; k < 4; ++k) {
    const int i4 = blk * 1024 + k * 256 + t;
    q[k]   = *(const int4*)(wq + base + (long)i4 * 4);
    nrm[k] = wn[l * 65536 + (i4 >> 2)];
  }
  if (slot >= 0) {
    const float* LAp = LA + (size_t)slot * 1048576;
#pragma unroll
    for (int k = 0; k < 4; ++k) {
      const int i4 = blk * 1024 + k * 256 + t;
      c4[k] = *(const float4*)(LAp + (size_t)i4 * 4);
    }
  }

  float v[4][4];
#pragma unroll
  for (int k = 0; k < 4; ++k) {
    v[k][0] = ((float)q[k].x * s - 1.0f) * nrm[k];
    v[k][1] = ((float)q[k].y * s - 1.0f) * nrm[k];
    v[k][2] = ((float)q[k].z * s - 1.0f) * nrm[k];
    v[k][3] = ((float)q[k].w * s - 1.0f) * nrm[k];
  }
  if (slot >= 0) {
#pragma unroll
    for (int k = 0; k < 4; ++k) {
      v[k][0] += c4[k].x; v[k][1] += c4[k].y;
      v[k][2] += c4[k].z; v[k][3] += c4[k].w;
    }
  }

#pragma unroll
  for (int k = 0; k < 4; ++k) {
    unsigned short u[4] = {f2bf(v[k][0]), f2bf(v[k][1]),
                           f2bf(v[k][2]), f2bf(v[k][3])};
    const long e0 = base + ((long)blk * 1024 + k * 256 + t) * 4;
    *(uint2*)(Wbf + e0) = *(uint2*)u;
  }
}

// ---------------------------------------------------------------------------
// fp32 -> bf16 for the initial x. grid 4096, block 256 (16 elems/thread).
// ---------------------------------------------------------------------------
__global__ __launch_bounds__(256) void cvt_bf16_kernel(
    const float* __restrict__ in, unsigned short* __restrict__ out) {
  const long b0 = (long)blockIdx.x * 4096 + threadIdx.x * 4;
  float4 v[4];
#pragma unroll
  for (int k = 0; k < 4; ++k) v[k] = *(const float4*)(in + b0 + k * 1024);
#pragma unroll
  for (int k = 0; k < 4; ++k) {
    unsigned short u[4] = {f2bf(v[k].x), f2bf(v[k].y), f2bf(v[k].z), f2bf(v[k].w)};
    *(ushort4*)(out + b0 + k * 1024) = *(ushort4*)u;
  }
}

// ---------------------------------------------------------------------------
// GEMM (proven, best measured): out[m][n] = sum_k H[m][k]*W[n][k] + bias[n].
// 128x128 tile, BK=64, 4 waves, 4 blocks/CU, grid 1024, block 256.
// mfma(af, bg): C/D col=lane&15 (n), row=quad*4+reg (m); scalar epilogue.
// MODE 0: relu + bf16 out. MODE 1: fp32 out. MODE 2: bf16 out (no relu).
// ---------------------------------------------------------------------------
template <int MODE>
__global__ __launch_bounds__(256, 4) void gemm_kernel(
    const unsigned short* __restrict__ H,
    const unsigned short* __restrict__ W,
    const float* __restrict__ bias,
    unsigned short* __restrict__ outb,
    float* __restrict__ outf) {
  constexpr int K = 1024;
  constexpr int NN = 1024;

  __shared__ uint4 ldsq[2048];              // 32 KiB
  char* base = (char*)ldsq;

  const int tid = threadIdx.x;
  const int w   = tid >> 6;
  const int ln  = tid & 63;
  const int b   = blockIdx.x;
  const int m0  = ((b & 7) * 16 + (b >> 6)) * 128;
  const int n0  = ((b >> 3) & 7) * 128;

  const int gc = (ln & 7) ^ (ln >> 3);
  const unsigned short* gA = H + (size_t)(m0 + w * 32 + (ln >> 3)) * K + gc * 8;
  const unsigned short* gB = W + (size_t)(n0 + w * 32 + (ln >> 3)) * K + gc * 8;
  char* ldsA = base + w * 4096;
  char* ldsB = base + 16384 + w * 4096;

  const int quad = ln >> 4;
  const int lrow = ln & 15;
  const int sw   = lrow & 7;
  const int c0   = ((quad)     ^ sw) * 16;
  const int c1   = ((quad + 4) ^ sw) * 16;
  const int wm   = (w >> 1) * 64;
  const int wn   = (w & 1) * 64;
  const char* fragA = base + (wm + lrow) * 128;
  const char* fragB = base + 16384 + (wn + lrow) * 128;

  f32x4 acc[4][4];
#pragma unroll
  for (int i = 0; i < 4; ++i)
#pragma unroll
    for (int j = 0; j < 4; ++j) acc[i][j] = (f32x4){0.f, 0.f, 0.f, 0.f};

  for (int kt = 0; kt < 16; ++kt) {
    const unsigned short* pA = gA + kt * 64;
    const unsigned short* pB = gB + kt * 64;
#pragma unroll
    for (int i = 0; i < 4; ++i) {
      async_copy16(ldsA + i * 1024, pA + (size_t)i * 8 * K);
      async_copy16(ldsB + i * 1024, pB + (size_t)i * 8 * K);
    }
    __syncthreads();
#pragma unroll
    for (int kk = 0; kk < 2; ++kk) {
      const int co = kk ? c1 : c0;
      bf16x8 af[4], bg[4];
#pragma unroll
      for (int mt = 0; mt < 4; ++mt)
        af[mt] = *(const bf16x8*)(fragA + mt * 2048 + co);
#pragma unroll
      for (int nt = 0; nt < 4; ++nt)
        bg[nt] = *(const bf16x8*)(fragB + nt * 2048 + co);
#pragma unroll
      for (int mt = 0; mt < 4; ++mt)
#pragma unroll
        for (int nt = 0; nt < 4; ++nt)
          acc[mt][nt] = __builtin_amdgcn_mfma_f32_16x16x32_bf16(
              af[mt], bg[nt], acc[mt][nt], 0, 0, 0);
    }
    __syncthreads();
  }

  // epilogue: C/D layout col=lane&15 (n), row=quad*4+reg (m)
#pragma unroll
  for (int nt = 0; nt < 4; ++nt) {
    const int n = n0 + wn + nt * 16 + lrow;
    const float bs = bias[n];
#pragma unroll
    for (int mt = 0; mt < 4; ++mt) {
      const int mb = m0 + wm + mt * 16 + quad * 4;
      f32x4 v = acc[mt][nt];
#pragma unroll
      for (int r = 0; r < 4; ++r) {
        float o = v[r] + bs;
        if (MODE == 0) o = fmaxf(o, 0.0f);
        if (MODE == 1) {
          outf[(size_t)(mb + r) * NN + n] = o;
        } else {
          outb[(size_t)(mb + r) * NN + n] = f2bf(o);
        }
      }
    }
  }
}

// ---------------------------------------------------------------------------
// LayerNorm (fp32 input; block 5 only). One WAVE per row. grid 4096, blk 256.
// ---------------------------------------------------------------------------
__global__ __launch_bounds__(256) void ln_kernel(
    const float* __restrict__ in, const float* __restrict__ lnw,
    const float* __restrict__ lnb, unsigned short* __restrict__ outb,
    float* __restrict__ outf, int wbf, int wf32) {
  const int wv = threadIdx.x >> 6;
  const int ln = threadIdx.x & 63;
  const int row = blockIdx.x * 4 + wv;
  const float* p = in + (size_t)row * 1024;

  float4 v[4];
  float s = 0.f, q = 0.f;
#pragma unroll
  for (int c = 0; c < 4; ++c) {
    v[c] = *(const float4*)(p + c * 256 + ln * 4);
    s += v[c].x + v[c].y + v[c].z + v[c].w;
    q += v[c].x * v[c].x + v[c].y * v[c].y + v[c].z * v[c].z + v[c].w * v[c].w;
  }
#pragma unroll
  for (int off = 32; off; off >>= 1) {
    s += __shfl_xor(s, off);
    q += __shfl_xor(q, off);
  }
  const float mu  = s * (1.0f / 1024.0f);
  const float var = q * (1.0f / 1024.0f) - mu * mu;
  const float rs  = rsqrtf(var + 1e-5f);

#pragma unroll
  for (int c = 0; c < 4; ++c) {
    const int col = c * 256 + ln * 4;
    const float4 w4 = *(const float4*)(lnw + col);
    const float4 b4 = *(const float4*)(lnb + col);
    const float y0 = (v[c].x - mu) * rs * w4.x + b4.x;
    const float y1 = (v[c].y - mu) * rs * w4.y + b4.y;
    const float y2 = (v[c].z - mu) * rs * w4.z + b4.z;
    const float y3 = (v[c].w - mu) * rs * w4.w + b4.w;
    if (wbf) {
      unsigned short u[4] = {f2bf(y0), f2bf(y1), f2bf(y2), f2bf(y3)};
      *(ushort4*)(outb + (size_t)row * 1024 + col) = *(ushort4*)u;
    }
    if (wf32) {
      float4 y = make_float4(y0, y1, y2, y3);
      *(float4*)(outf + (size_t)row * 1024 + col) = y;
    }
  }
}

// ---------------------------------------------------------------------------
// LayerNorm, bf16 in -> bf16 out (blocks 0-4). One WAVE per row; lane owns
// cols [ln*16, ln*16+16). grid 4096, block 256.
// ---------------------------------------------------------------------------
__global__ __launch_bounds__(256) void ln_bf16_kernel(
    const unsigned short* __restrict__ in, const float* __restrict__ lnw,
    const float* __restrict__ lnb, unsigned short* __restrict__ outb) {
  const int wv = threadIdx.x >> 6;
  const int ln = threadIdx.x & 63;
  const int row = blockIdx.x * 4 + wv;
  const unsigned short* p = in + (size_t)row * 1024 + ln * 16;

  const uint4 r0 = *(const uint4*)(p);
  const uint4 r1 = *(const uint4*)(p + 8);
  const unsigned ru[8] = {r0.x, r0.y, r0.z, r0.w, r1.x, r1.y, r1.z, r1.w};

  float f[16];
#pragma unroll
  for (int i = 0; i < 8; ++i) {
    f[2 * i]     = __builtin_bit_cast(float, ru[i] << 16);
    f[2 * i + 1] = __builtin_bit_cast(float, ru[i] & 0xffff0000u);
  }

  float s = 0.f, q = 0.f;
#pragma unroll
  for (int i = 0; i < 16; ++i) { s += f[i]; q += f[i] * f[i]; }
#pragma unroll
  for (int off = 32; off; off >>= 1) {
    s += __shfl_xor(s, off);
    q += __shfl_xor(q, off);
  }
  const float mu  = s * (1.0f / 1024.0f);
  const float var = q * (1.0f / 1024.0f) - mu * mu;
  const float rs  = rsqrtf(var + 1e-5f);

  const float* wp = lnw + ln * 16;
  const float* bp = lnb + ln * 16;
  unsigned o[8];
#pragma unroll
  for (int i = 0; i < 8; ++i) {
    const float y0 = (f[2 * i]     - mu) * rs * wp[2 * i]     + bp[2 * i];
    const float y1 = (f[2 * i + 1] - mu) * rs * wp[2 * i + 1] + bp[2 * i + 1];
    o[i] = (unsigned)f2bf(y0) | ((unsigned)f2bf(y1) << 16);
  }
  unsigned short* dst = outb + (size_t)row * 1024 + ln * 16;
  *(uint4*)(dst)     = make_uint4(o[0], o[1], o[2], o[3]);
  *(uint4*)(dst + 8) = make_uint4(o[4], o[5], o[6], o[7]);
}

// ---------------------------------------------------------------------------
extern "C" void kernel_launch(void* const* d_in, const int* in_sizes, int n_in,
                              void* d_out, int out_size, void* d_ws, size_t ws_size,
                              hipStream_t stream) {
  const float* x    = (const float*)d_in[0];
  const int*   wq   = (const int*)d_in[1];
  const float* wn   = (const float*)d_in[2];
  const float* bias = (const float*)d_in[3];
  const float* la   = (const float*)d_in[4];
  const float* lb   = (const float*)d_in[5];
  const float* lnw  = (const float*)d_in[6];
  const float* lnb  = (const float*)d_in[7];
  float* out = (float*)d_out;

  char* ws = (char*)d_ws;
  unsigned short* Wbf = (unsigned short*)ws;                         // 37.75 MB
  unsigned short* hA  = (unsigned short*)(ws + 37748736);            // 32 MB
  unsigned short* hB  = (unsigned short*)(ws + 37748736 + 33554432); // 32 MB
  float* LA = (float*)hB;   // 12 MB, consumed by dequant before hB is written

  lora_kernel<<<dim3(256, 3), 256, 0, stream>>>(la, lb, LA);
  dequant_kernel<<<dim3(256, 18), 256, 0, stream>>>(wq, wn, LA, Wbf);
  cvt_bf16_kernel<<<4096, 256, 0, stream>>>(x, hA);

  for (int blk = 0; blk < 6; ++blk) {
    const int l = blk * 3;
    gemm_kernel<0><<<1024, 256, 0, stream>>>(
        hA, Wbf + (size_t)l * 1048576, bias + l * 1024, hB, nullptr);
    gemm_kernel<0><<<1024, 256, 0, stream>>>(
        hB, Wbf + (size_t)(l + 1) * 1048576, bias + (l + 1) * 1024, hA, nullptr);
    if (blk < 5) {
      gemm_kernel<2><<<1024, 256, 0, stream>>>(
          hA, Wbf + (size_t)(l + 2) * 1048576, bias + (l + 2) * 1024, hB, nullptr);
      ln_bf16_kernel<<<4096, 256, 0, stream>>>(
          hB, lnw + blk * 1024, lnb + blk * 1024, hA);
    } else {
      gemm_kernel<1><<<1024, 256, 0, stream>>>(
          hA, Wbf + (size_t)(l + 2) * 1048576, bias + (l + 2) * 1024, nullptr, out);
      ln_kernel<<<4096, 256, 0, stream>>>(
          out, lnw + blk * 1024, lnb + blk * 1024, nullptr, out, 0, 1);
    }
  }
}